// Round 7
// baseline (243.070 us; speedup 1.0000x reference)
//
#include <hip/hip_runtime.h>
#include <cfloat>

// VectorQuantizer: inputs [65536,64] f32, embeddings [2048,64] f32
#define N_TOTAL 65536
#define DIM     64
#define NEMB    2048

typedef __attribute__((ext_vector_type(8))) _Float16 half8;   // MFMA A/B frag (4 VGPRs)
typedef __attribute__((ext_vector_type(4))) float    floatx4; // MFMA C/D frag

__device__ __forceinline__ unsigned umin2(unsigned a, unsigned b) { return a < b ? a : b; }
__device__ __forceinline__ unsigned umax2(unsigned a, unsigned b) { return a > b ? a : b; }

// ---------------------------------------------------------------------------
// Prep: pack embeddings as f16 (single limb) in MFMA-B frag-major layout
//   chunk c = (g*2 + ks)*64 + lane, lane = q*16 + n:
//   ehp[c] = e_f16[col = g*16+n][k = ks*32 + q*8 .. +8)
// One 32-col tile = 4 chunks = 4 KB contiguous.
// Norms stored pre-folded: en'[k] = 128 - 0.5*||e_k||^2  (acc init = v_mov).
// ---------------------------------------------------------------------------
__global__ void prep_kernel(const float* __restrict__ emb,
                            half8* __restrict__ ehp, float* __restrict__ en) {
    const int t = blockIdx.x * 256 + threadIdx.x;   // 16384 threads
    {
        const int l   = t & 63;
        const int ks  = (t >> 6) & 1;
        const int g   = t >> 7;
        const int col = g * 16 + (l & 15);
        const int kb  = ks * 32 + (l >> 4) * 8;
        const float* s = emb + col * DIM + kb;
        float4 v0 = *(const float4*)s, v1 = *(const float4*)(s + 4);
        half8 hv;
        hv[0] = (_Float16)v0.x; hv[1] = (_Float16)v0.y;
        hv[2] = (_Float16)v0.z; hv[3] = (_Float16)v0.w;
        hv[4] = (_Float16)v1.x; hv[5] = (_Float16)v1.y;
        hv[6] = (_Float16)v1.z; hv[7] = (_Float16)v1.w;
        ehp[t] = hv;
    }
    if (t < NEMB * 4) {
        const int row = t >> 2, seg = t & 3;
        const float* s = emb + row * DIM + seg * 16;
        float acc = 0.f;
#pragma unroll
        for (int i = 0; i < 4; ++i) {
            float4 v = ((const float4*)s)[i];
            acc = fmaf(v.x, v.x, acc); acc = fmaf(v.y, v.y, acc);
            acc = fmaf(v.z, v.z, acc); acc = fmaf(v.w, v.w, acc);
        }
        acc += __shfl_xor(acc, 1, 64);
        acc += __shfl_xor(acc, 2, 64);
        if (seg == 0) en[row] = fmaf(-0.5f, acc, 128.0f);
    }
}

// ---------------------------------------------------------------------------
// Main. Block = 4 waves, 32 rows. All 4 waves share the SAME 32 rows; wave
// h scans codebook quarter [h*512, +512) in 16 tiles of 32 cols. 2048 blocks
// -> 8192 waves = 8/SIMD (grid-limited TLP fixed). B-fragments streamed
// straight to VGPRs (ping-pong register prefetch, zero barriers in K-loop).
//   approx q = x_f16 . e_f16 + (128 - ||e||^2/2)   (1-limb; rescue below)
//   packed key = (bits(q) & ~63) | (63-L); branchless top-2 min/max/max.
//   4 independent MFMA acc chains per tile (depth 2) for ILP.
// Epilogue: exact fp32 rescore of 8 candidates (top-2 per quarter);
// tie -> lower col. Final index is fp32-exact.
// ---------------------------------------------------------------------------
__global__ __launch_bounds__(256, 6) void vq_mfma_kernel(
        const float* __restrict__ x, const float* __restrict__ emb,
        const char* __restrict__ ehb, const float* __restrict__ eng,
        float* __restrict__ quant, float* __restrict__ idxf,
        float* __restrict__ flat) {

    __shared__ float EnS[NEMB];          // 8 KB: all folded norms
    __shared__ uint4 Mrg[4][32];         // 2 KB: per-quarter top-2 candidates

    const int t    = threadIdx.x;
    const int h    = t >> 6, lane = t & 63;   // wave id == codebook quarter
    const int n = lane & 15, q = lane >> 4;
    const int blk0 = blockIdx.x * 32;

    // ---- flat_inputs copy (block-coalesced, 32 rows = 512 float4) ----
    {
        const float4* s4 = (const float4*)(x + (size_t)blk0 * DIM);
        float4*       d4 = (float4*)(flat + (size_t)blk0 * DIM);
#pragma unroll
        for (int i = 0; i < 2; ++i) d4[i * 256 + t] = s4[i * 256 + t];
    }
    // ---- stage all folded norms to LDS ----
    {
        const float4* s4 = (const float4*)eng;
        float4*       d4 = (float4*)EnS;
#pragma unroll
        for (int i = 0; i < 2; ++i) d4[i * 256 + t] = s4[i * 256 + t];
    }

    // ---- A fragments (1 limb). A[m=lane&15][k=q*8+j]; rows blk0+tl*16+n ----
    half8 ah[2][2];
#pragma unroll
    for (int tl = 0; tl < 2; ++tl)
#pragma unroll
        for (int ks = 0; ks < 2; ++ks) {
            const float* pp = x + (size_t)(blk0 + tl * 16 + n) * DIM + ks * 32 + q * 8;
            float4 v0 = *(const float4*)pp, v1 = *(const float4*)(pp + 4);
            ah[tl][ks][0] = (_Float16)v0.x; ah[tl][ks][1] = (_Float16)v0.y;
            ah[tl][ks][2] = (_Float16)v0.z; ah[tl][ks][3] = (_Float16)v0.w;
            ah[tl][ks][4] = (_Float16)v1.x; ah[tl][ks][5] = (_Float16)v1.y;
            ah[tl][ks][6] = (_Float16)v1.z; ah[tl][ks][7] = (_Float16)v1.w;
        }

    __syncthreads();   // EnS visible

    unsigned best[8], sec[8];
#pragma unroll
    for (int r = 0; r < 8; ++r) { best[r] = 0u; sec[r] = 0u; }

    // quarter h = global tiles [h*16, h*16+16); 4 KB per tile, lane*16 within
    const char* ebase = ehb + (size_t)h * 65536 + (size_t)lane * 16;

    half8 bbuf[2][4];
    float enc[2][2];
    // ---- prologue: tile 0 ----
#pragma unroll
    for (int i = 0; i < 4; ++i)
        bbuf[0][i] = *(const half8*)(ebase + i * 1024);
#pragma unroll
    for (int s = 0; s < 2; ++s)
        enc[0][s] = EnS[h * 512 + s * 16 + n];

#pragma unroll 2
    for (int tile = 0; tile < 16; ++tile) {
        const int buf = tile & 1;
        if (tile < 15) {
            const char* src = ebase + (size_t)(tile + 1) * 4096;
#pragma unroll
            for (int i = 0; i < 4; ++i)
                bbuf[buf ^ 1][i] = *(const half8*)(src + i * 1024);
#pragma unroll
            for (int s = 0; s < 2; ++s)
                enc[buf ^ 1][s] = EnS[h * 512 + (tile + 1) * 32 + s * 16 + n];
        }

        // ---- 4 independent acc chains (2 subtiles x 2 row-groups), depth 2 ----
        const float e0 = enc[buf][0], e1 = enc[buf][1];
        floatx4 A0 = {e0, e0, e0, e0};   // sub0, rows 0-15
        floatx4 A1 = {e0, e0, e0, e0};   // sub0, rows 16-31
        floatx4 A2 = {e1, e1, e1, e1};   // sub1, rows 0-15
        floatx4 A3 = {e1, e1, e1, e1};   // sub1, rows 16-31
        A0 = __builtin_amdgcn_mfma_f32_16x16x32_f16(ah[0][0], bbuf[buf][0], A0, 0, 0, 0);
        A1 = __builtin_amdgcn_mfma_f32_16x16x32_f16(ah[1][0], bbuf[buf][0], A1, 0, 0, 0);
        A2 = __builtin_amdgcn_mfma_f32_16x16x32_f16(ah[0][0], bbuf[buf][2], A2, 0, 0, 0);
        A3 = __builtin_amdgcn_mfma_f32_16x16x32_f16(ah[1][0], bbuf[buf][2], A3, 0, 0, 0);
        A0 = __builtin_amdgcn_mfma_f32_16x16x32_f16(ah[0][1], bbuf[buf][1], A0, 0, 0, 0);
        A1 = __builtin_amdgcn_mfma_f32_16x16x32_f16(ah[1][1], bbuf[buf][1], A1, 0, 0, 0);
        A2 = __builtin_amdgcn_mfma_f32_16x16x32_f16(ah[0][1], bbuf[buf][3], A2, 0, 0, 0);
        A3 = __builtin_amdgcn_mfma_f32_16x16x32_f16(ah[1][1], bbuf[buf][3], A3, 0, 0, 0);

        const unsigned Lp0 = (unsigned)(63 - (tile * 2 + 0));
        const unsigned Lp1 = (unsigned)(63 - (tile * 2 + 1));
#pragma unroll
        for (int r = 0; r < 8; ++r) {
            float v0 = (r < 4) ? A0[r] : A1[r - 4];
            unsigned k0 = (__float_as_uint(v0) & 0xFFFFFFC0u) | Lp0;
            unsigned lo0 = umin2(best[r], k0);
            best[r] = umax2(best[r], k0);
            sec[r]  = umax2(sec[r], lo0);
            float v1 = (r < 4) ? A2[r] : A3[r - 4];
            unsigned k1 = (__float_as_uint(v1) & 0xFFFFFFC0u) | Lp1;
            unsigned lo1 = umin2(best[r], k1);
            best[r] = umax2(best[r], k1);
            sec[r]  = umax2(sec[r], lo1);
        }
    }

    // ---- decode per-lane top-2 to (bucketed bits, full col) ----
    unsigned bval[8], bcol[8], sval[8], scol[8];
#pragma unroll
    for (int r = 0; r < 8; ++r) {
        bval[r] = best[r] & 0xFFFFFFC0u;
        bcol[r] = (unsigned)(h * 512 + (63 - (int)(best[r] & 63u)) * 16 + n);
        sval[r] = sec[r] & 0xFFFFFFC0u;
        scol[r] = (unsigned)(h * 512 + (63 - (int)(sec[r] & 63u)) * 16 + n);
    }
    // ---- butterfly top-2 merge across the 16 n-lanes of each q-group ----
#pragma unroll
    for (int m = 1; m < 16; m <<= 1) {
#pragma unroll
        for (int r = 0; r < 8; ++r) {
            unsigned ov  = (unsigned)__shfl_xor((int)bval[r], m, 64);
            unsigned oc  = (unsigned)__shfl_xor((int)bcol[r], m, 64);
            unsigned ov2 = (unsigned)__shfl_xor((int)sval[r], m, 64);
            unsigned oc2 = (unsigned)__shfl_xor((int)scol[r], m, 64);
            bool ow = (ov > bval[r]) || (ov == bval[r] && oc < bcol[r]);
            unsigned nbv = ow ? ov : bval[r], nbc = ow ? oc : bcol[r];
            unsigned lv  = ow ? bval[r] : ov, lc  = ow ? bcol[r] : oc;
            bool sv2 = (ov2 > sval[r]) || (ov2 == sval[r] && oc2 < scol[r]);
            unsigned bsv = sv2 ? ov2 : sval[r], bsc = sv2 ? oc2 : scol[r];
            bool s3 = (lv > bsv) || (lv == bsv && lc < bsc);
            sval[r] = s3 ? lv : bsv; scol[r] = s3 ? lc : bsc;
            bval[r] = nbv; bcol[r] = nbc;
        }
    }
    // ---- publish per-quarter candidates (local row = tl*16 + q*4 + r&3) ----
    if (n == 0) {
#pragma unroll
        for (int r = 0; r < 8; ++r) {
            const int lr = (r >> 2) * 16 + q * 4 + (r & 3);
            Mrg[h][lr] = make_uint4(bval[r], bcol[r], sval[r], scol[r]);
        }
    }
    __syncthreads();

    // ---- exact fp32 rescore of 8 candidates; wave w: rows [w*8, w*8+8) ----
#pragma unroll
    for (int rr = 0; rr < 2; ++rr) {
        const int lr   = h * 8 + q * 2 + rr;
        const int grow = blk0 + lr;
        int cand[8];
#pragma unroll
        for (int g = 0; g < 4; ++g) {
            uint4 cv = Mrg[g][lr];
            cand[g * 2 + 0] = (int)cv.y;
            cand[g * 2 + 1] = (int)cv.w;
        }
        float4 xv = *(const float4*)(x + (size_t)grow * DIM + n * 4);
        float pbest = -FLT_MAX; int cbest = 0;
        float4 ebest = {0.f, 0.f, 0.f, 0.f};
#pragma unroll
        for (int c = 0; c < 8; ++c) {
            float4 e = *(const float4*)(emb + (size_t)cand[c] * DIM + n * 4);
            float pp = (xv.x - 0.5f * e.x) * e.x + (xv.y - 0.5f * e.y) * e.y
                     + (xv.z - 0.5f * e.z) * e.z + (xv.w - 0.5f * e.w) * e.w;
#pragma unroll
            for (int m2 = 1; m2 < 16; m2 <<= 1) pp += __shfl_xor(pp, m2, 64);
            bool take = (pp > pbest) || (pp == pbest && cand[c] < cbest);
            pbest = take ? pp : pbest;
            cbest = take ? cand[c] : cbest;
            ebest.x = take ? e.x : ebest.x; ebest.y = take ? e.y : ebest.y;
            ebest.z = take ? e.z : ebest.z; ebest.w = take ? e.w : ebest.w;
        }
        *(float4*)(quant + (size_t)grow * DIM + n * 4) = ebest;
        if (n == 0) idxf[grow] = (float)cbest;
    }
}

extern "C" void kernel_launch(void* const* d_in, const int* in_sizes, int n_in,
                              void* d_out, int out_size, void* d_ws, size_t ws_size,
                              hipStream_t stream) {
    const float* x   = (const float*)d_in[0];   // [65536, 64]
    const float* emb = (const float*)d_in[1];   // [2048, 64]
    float* out   = (float*)d_out;
    float* quant = out;                               // 4194304 floats
    float* idxf  = out + (size_t)N_TOTAL * DIM;       // 65536 floats
    float* flat  = idxf + N_TOTAL;                    // 4194304 floats

    half8* ehp = (half8*)d_ws;                        // 2048*64 f16 frag-major (256 KB)
    float* en  = (float*)((char*)d_ws + (size_t)NEMB * DIM * 2);  // 2048 f32 (folded)

    prep_kernel<<<64, 256, 0, stream>>>(emb, ehp, en);
    vq_mfma_kernel<<<N_TOTAL / 32, 256, 0, stream>>>(x, emb, (const char*)ehp, en,
                                                     quant, idxf, flat);
}

// Round 8
// 161.222 us; speedup vs baseline: 1.5077x; 1.5077x over previous
//
#include <hip/hip_runtime.h>
#include <cfloat>

// VectorQuantizer: inputs [65536,64] f32, embeddings [2048,64] f32
#define N_TOTAL 65536
#define DIM     64
#define NEMB    2048

typedef __attribute__((ext_vector_type(8))) _Float16 half8;   // MFMA A/B frag (4 VGPRs)
typedef __attribute__((ext_vector_type(4))) float    floatx4; // MFMA C/D frag

__device__ __forceinline__ unsigned umin2(unsigned a, unsigned b) { return a < b ? a : b; }
__device__ __forceinline__ unsigned umax2(unsigned a, unsigned b) { return a > b ? a : b; }

// ---------------------------------------------------------------------------
// Prep: pack embeddings as f16 (single limb) in MFMA-B frag-major layout
//   chunk c = (g*2 + ks)*64 + lane, lane = q*16 + n:
//   ehp[c] = e_f16[col = g*16+n][k = ks*32 + q*8 .. +8)
// One 16-col tile = 2 chunks = 2 KB contiguous.
// Norms stored pre-folded: en'[k] = 128 - 0.5*||e_k||^2  (acc init = v_mov).
// ---------------------------------------------------------------------------
__global__ void prep_kernel(const float* __restrict__ emb,
                            half8* __restrict__ ehp, float* __restrict__ en) {
    const int t = blockIdx.x * 256 + threadIdx.x;   // 16384 threads
    {
        const int l   = t & 63;
        const int ks  = (t >> 6) & 1;
        const int g   = t >> 7;
        const int col = g * 16 + (l & 15);
        const int kb  = ks * 32 + (l >> 4) * 8;
        const float* s = emb + col * DIM + kb;
        float4 v0 = *(const float4*)s, v1 = *(const float4*)(s + 4);
        half8 hv;
        hv[0] = (_Float16)v0.x; hv[1] = (_Float16)v0.y;
        hv[2] = (_Float16)v0.z; hv[3] = (_Float16)v0.w;
        hv[4] = (_Float16)v1.x; hv[5] = (_Float16)v1.y;
        hv[6] = (_Float16)v1.z; hv[7] = (_Float16)v1.w;
        ehp[t] = hv;
    }
    if (t < NEMB * 4) {
        const int row = t >> 2, seg = t & 3;
        const float* s = emb + row * DIM + seg * 16;
        float acc = 0.f;
#pragma unroll
        for (int i = 0; i < 4; ++i) {
            float4 v = ((const float4*)s)[i];
            acc = fmaf(v.x, v.x, acc); acc = fmaf(v.y, v.y, acc);
            acc = fmaf(v.z, v.z, acc); acc = fmaf(v.w, v.w, acc);
        }
        acc += __shfl_xor(acc, 1, 64);
        acc += __shfl_xor(acc, 2, 64);
        if (seg == 0) en[row] = fmaf(-0.5f, acc, 128.0f);
    }
}

// ---------------------------------------------------------------------------
// Main. Block = 4 waves, 32 rows (all waves share the rows); wave h scans
// codebook quarter [h*512, +512) in 32 tiles of 16 cols. 2048 blocks ->
// 8192 waves = 8/SIMD. State sized for <=64 VGPRs (launch_bounds(256,8)):
// single-buffered B frags (8 regs), 2 acc chains, norms read from global
// (L1/L2-resident, no LDS cache). TLP (8 waves) hides per-tile L2 latency;
// zero barriers in the K-loop.
//   approx q = x_f16 . e_f16 + (128 - ||e||^2/2)   (1-limb)
//   packed key = (bits(q) & ~63) | (63 - tile); branchless top-2.
// Epilogue: butterfly merge (col tiebreak), exact fp32 rescore of 8
// candidates (top-2 per quarter); tie -> lower col. Index fp32-exact.
// ---------------------------------------------------------------------------
__global__ __launch_bounds__(256, 8) void vq_mfma_kernel(
        const float* __restrict__ x, const float* __restrict__ emb,
        const char* __restrict__ ehb, const float* __restrict__ eng,
        float* __restrict__ quant, float* __restrict__ idxf,
        float* __restrict__ flat) {

    __shared__ uint4 Mrg[4][32];         // 2 KB: per-quarter top-2 candidates

    const int t    = threadIdx.x;
    const int h    = t >> 6, lane = t & 63;   // wave id == codebook quarter
    const int n = lane & 15, q = lane >> 4;
    const int blk0 = blockIdx.x * 32;

    // ---- flat_inputs copy (block-coalesced, 32 rows = 512 float4) ----
    {
        const float4* s4 = (const float4*)(x + (size_t)blk0 * DIM);
        float4*       d4 = (float4*)(flat + (size_t)blk0 * DIM);
        d4[t]       = s4[t];
        d4[256 + t] = s4[256 + t];
    }

    // ---- A fragments (1 limb). A[m=lane&15][k=q*8+j]; rows blk0+tl*16+n ----
    half8 ah[2][2];
#pragma unroll
    for (int tl = 0; tl < 2; ++tl)
#pragma unroll
        for (int ks = 0; ks < 2; ++ks) {
            const float* pp = x + (size_t)(blk0 + tl * 16 + n) * DIM + ks * 32 + q * 8;
            float4 v0 = *(const float4*)pp, v1 = *(const float4*)(pp + 4);
            ah[tl][ks][0] = (_Float16)v0.x; ah[tl][ks][1] = (_Float16)v0.y;
            ah[tl][ks][2] = (_Float16)v0.z; ah[tl][ks][3] = (_Float16)v0.w;
            ah[tl][ks][4] = (_Float16)v1.x; ah[tl][ks][5] = (_Float16)v1.y;
            ah[tl][ks][6] = (_Float16)v1.z; ah[tl][ks][7] = (_Float16)v1.w;
        }

    unsigned best[8], sec[8];
#pragma unroll
    for (int r = 0; r < 8; ++r) { best[r] = 0u; sec[r] = 0u; }

    // quarter h: tiles of 16 cols, 2 KB each; per-lane frag at lane*16
    const char*  ebase = ehb + (size_t)h * 65536 + (size_t)lane * 16;
    const float* enq   = eng + h * 512 + n;

#pragma unroll 2
    for (int tile = 0; tile < 32; ++tile) {
        half8 b0 = *(const half8*)(ebase + tile * 2048);
        half8 b1 = *(const half8*)(ebase + tile * 2048 + 1024);
        const float en = enq[tile * 16];

        floatx4 A0 = {en, en, en, en};   // rows 0-15
        floatx4 A1 = {en, en, en, en};   // rows 16-31
        A0 = __builtin_amdgcn_mfma_f32_16x16x32_f16(ah[0][0], b0, A0, 0, 0, 0);
        A1 = __builtin_amdgcn_mfma_f32_16x16x32_f16(ah[1][0], b0, A1, 0, 0, 0);
        A0 = __builtin_amdgcn_mfma_f32_16x16x32_f16(ah[0][1], b1, A0, 0, 0, 0);
        A1 = __builtin_amdgcn_mfma_f32_16x16x32_f16(ah[1][1], b1, A1, 0, 0, 0);

        const unsigned Lp = (unsigned)(63 - tile);
#pragma unroll
        for (int r = 0; r < 8; ++r) {
            float v = (r < 4) ? A0[r] : A1[r - 4];
            unsigned key = (__float_as_uint(v) & 0xFFFFFFC0u) | Lp;  // v_and_or_b32
            unsigned lo  = umin2(best[r], key);
            best[r] = umax2(best[r], key);
            sec[r]  = umax2(sec[r], lo);
        }
    }

    // ---- decode per-lane top-2 to (bucketed bits, full col) ----
    unsigned bval[8], bcol[8], sval[8], scol[8];
#pragma unroll
    for (int r = 0; r < 8; ++r) {
        bval[r] = best[r] & 0xFFFFFFC0u;
        bcol[r] = (unsigned)(h * 512 + (63 - (int)(best[r] & 63u)) * 16 + n);
        sval[r] = sec[r] & 0xFFFFFFC0u;
        scol[r] = (unsigned)(h * 512 + (63 - (int)(sec[r] & 63u)) * 16 + n);
    }
    // ---- butterfly top-2 merge across the 16 n-lanes of each q-group ----
#pragma unroll
    for (int m = 1; m < 16; m <<= 1) {
#pragma unroll
        for (int r = 0; r < 8; ++r) {
            unsigned ov  = (unsigned)__shfl_xor((int)bval[r], m, 64);
            unsigned oc  = (unsigned)__shfl_xor((int)bcol[r], m, 64);
            unsigned ov2 = (unsigned)__shfl_xor((int)sval[r], m, 64);
            unsigned oc2 = (unsigned)__shfl_xor((int)scol[r], m, 64);
            bool ow = (ov > bval[r]) || (ov == bval[r] && oc < bcol[r]);
            unsigned nbv = ow ? ov : bval[r], nbc = ow ? oc : bcol[r];
            unsigned lv  = ow ? bval[r] : ov, lc  = ow ? bcol[r] : oc;
            bool sv2 = (ov2 > sval[r]) || (ov2 == sval[r] && oc2 < scol[r]);
            unsigned bsv = sv2 ? ov2 : sval[r], bsc = sv2 ? oc2 : scol[r];
            bool s3 = (lv > bsv) || (lv == bsv && lc < bsc);
            sval[r] = s3 ? lv : bsv; scol[r] = s3 ? lc : bsc;
            bval[r] = nbv; bcol[r] = nbc;
        }
    }
    // ---- publish per-quarter candidates (local row = (r>>2)*16 + q*4 + r&3) ----
    if (n == 0) {
#pragma unroll
        for (int r = 0; r < 8; ++r) {
            const int lr = (r >> 2) * 16 + q * 4 + (r & 3);
            Mrg[h][lr] = make_uint4(bval[r], bcol[r], sval[r], scol[r]);
        }
    }
    __syncthreads();

    // ---- exact fp32 rescore of 8 candidates; wave h: rows [h*8, h*8+8) ----
#pragma unroll
    for (int rr = 0; rr < 2; ++rr) {
        const int lr   = h * 8 + q * 2 + rr;
        const int grow = blk0 + lr;
        int cand[8];
#pragma unroll
        for (int g = 0; g < 4; ++g) {
            uint4 cv = Mrg[g][lr];
            cand[g * 2 + 0] = (int)cv.y;
            cand[g * 2 + 1] = (int)cv.w;
        }
        float4 xv = *(const float4*)(x + (size_t)grow * DIM + n * 4);
        float pbest = -FLT_MAX; int cbest = 0;
        float4 ebest = {0.f, 0.f, 0.f, 0.f};
#pragma unroll
        for (int c = 0; c < 8; ++c) {
            float4 e = *(const float4*)(emb + (size_t)cand[c] * DIM + n * 4);
            float pp = (xv.x - 0.5f * e.x) * e.x + (xv.y - 0.5f * e.y) * e.y
                     + (xv.z - 0.5f * e.z) * e.z + (xv.w - 0.5f * e.w) * e.w;
#pragma unroll
            for (int m2 = 1; m2 < 16; m2 <<= 1) pp += __shfl_xor(pp, m2, 64);
            bool take = (pp > pbest) || (pp == pbest && cand[c] < cbest);
            pbest = take ? pp : pbest;
            cbest = take ? cand[c] : cbest;
            ebest.x = take ? e.x : ebest.x; ebest.y = take ? e.y : ebest.y;
            ebest.z = take ? e.z : ebest.z; ebest.w = take ? e.w : ebest.w;
        }
        *(float4*)(quant + (size_t)grow * DIM + n * 4) = ebest;
        if (n == 0) idxf[grow] = (float)cbest;
    }
}

extern "C" void kernel_launch(void* const* d_in, const int* in_sizes, int n_in,
                              void* d_out, int out_size, void* d_ws, size_t ws_size,
                              hipStream_t stream) {
    const float* x   = (const float*)d_in[0];   // [65536, 64]
    const float* emb = (const float*)d_in[1];   // [2048, 64]
    float* out   = (float*)d_out;
    float* quant = out;                               // 4194304 floats
    float* idxf  = out + (size_t)N_TOTAL * DIM;       // 65536 floats
    float* flat  = idxf + N_TOTAL;                    // 4194304 floats

    half8* ehp = (half8*)d_ws;                        // 2048*64 f16 frag-major (256 KB)
    float* en  = (float*)((char*)d_ws + (size_t)NEMB * DIM * 2);  // 2048 f32 (folded)

    prep_kernel<<<64, 256, 0, stream>>>(emb, ehp, en);
    vq_mfma_kernel<<<N_TOTAL / 32, 256, 0, stream>>>(x, emb, (const char*)ehp, en,
                                                     quant, idxf, flat);
}

// Round 9
// 122.720 us; speedup vs baseline: 1.9807x; 1.3137x over previous
//
#include <hip/hip_runtime.h>
#include <cfloat>

// VectorQuantizer: inputs [65536,64] f32, embeddings [2048,64] f32
#define N_TOTAL 65536
#define DIM     64
#define NEMB    2048

typedef __attribute__((ext_vector_type(8))) _Float16 half8;   // MFMA A/B frag (4 VGPRs)
typedef __attribute__((ext_vector_type(4))) float    floatx4; // MFMA C/D frag

__device__ __forceinline__ unsigned umin2(unsigned a, unsigned b) { return a < b ? a : b; }
__device__ __forceinline__ unsigned umax2(unsigned a, unsigned b) { return a > b ? a : b; }

// ---------------------------------------------------------------------------
// Prep: pack embeddings as f16 (single limb) in MFMA-B frag-major layout
//   chunk c = (g*2 + ks)*64 + lane, lane = q*16 + n:
//   ehp[c] = e_f16[col = g*16+n][k = ks*32 + q*8 .. +8)
// One 16-col tile = 2 chunks = 2 KB contiguous.
// Norms stored pre-folded: en'[k] = 128 - 0.5*||e_k||^2  (acc init = v_mov).
// ---------------------------------------------------------------------------
__global__ void prep_kernel(const float* __restrict__ emb,
                            half8* __restrict__ ehp, float* __restrict__ en) {
    const int t = blockIdx.x * 256 + threadIdx.x;   // 16384 threads
    {
        const int l   = t & 63;
        const int ks  = (t >> 6) & 1;
        const int g   = t >> 7;
        const int col = g * 16 + (l & 15);
        const int kb  = ks * 32 + (l >> 4) * 8;
        const float* s = emb + col * DIM + kb;
        float4 v0 = *(const float4*)s, v1 = *(const float4*)(s + 4);
        half8 hv;
        hv[0] = (_Float16)v0.x; hv[1] = (_Float16)v0.y;
        hv[2] = (_Float16)v0.z; hv[3] = (_Float16)v0.w;
        hv[4] = (_Float16)v1.x; hv[5] = (_Float16)v1.y;
        hv[6] = (_Float16)v1.z; hv[7] = (_Float16)v1.w;
        ehp[t] = hv;
    }
    if (t < NEMB * 4) {
        const int row = t >> 2, seg = t & 3;
        const float* s = emb + row * DIM + seg * 16;
        float acc = 0.f;
#pragma unroll
        for (int i = 0; i < 4; ++i) {
            float4 v = ((const float4*)s)[i];
            acc = fmaf(v.x, v.x, acc); acc = fmaf(v.y, v.y, acc);
            acc = fmaf(v.z, v.z, acc); acc = fmaf(v.w, v.w, acc);
        }
        acc += __shfl_xor(acc, 1, 64);
        acc += __shfl_xor(acc, 2, 64);
        if (seg == 0) en[row] = fmaf(-0.5f, acc, 128.0f);
    }
}

// ---------------------------------------------------------------------------
// Main. Block = 4 waves, 32 rows (all waves share the rows); wave h scans
// codebook quarter [h*512, +512) in 32 tiles of 16 cols. 2048 blocks ->
// 8192 waves = 8/SIMD of TLP. launch_bounds(256,4): generous 128-reg
// ceiling so the allocator does NOT spill (R7/R8 post-mortem: bounds >=6
// force a 32-40 arch-VGPR split and catastrophic scratch traffic); actual
// state ~48 arch + 8 acc, expected alloc <=64 -> HW residency 8 waves/SIMD
// (m69: waves halve at vgpr={64,128}).
//   approx q = x_f16 . e_f16 + (128 - ||e||^2/2)   (1-limb)
//   packed key = (bits(q) & ~63) | (63 - tile); branchless top-2.
// Epilogue: butterfly merge (col tiebreak), exact fp32 rescore of 8
// candidates (top-2 per quarter); tie -> lower col. Index fp32-exact.
// ---------------------------------------------------------------------------
__global__ __launch_bounds__(256, 4) void vq_mfma_kernel(
        const float* __restrict__ x, const float* __restrict__ emb,
        const char* __restrict__ ehb, const float* __restrict__ eng,
        float* __restrict__ quant, float* __restrict__ idxf,
        float* __restrict__ flat) {

    __shared__ uint4 Mrg[4][32];         // 2 KB: per-quarter top-2 candidates

    const int t    = threadIdx.x;
    const int h    = t >> 6, lane = t & 63;   // wave id == codebook quarter
    const int n = lane & 15, q = lane >> 4;
    const int blk0 = blockIdx.x * 32;

    // ---- flat_inputs copy (block-coalesced, 32 rows = 512 float4) ----
    {
        const float4* s4 = (const float4*)(x + (size_t)blk0 * DIM);
        float4*       d4 = (float4*)(flat + (size_t)blk0 * DIM);
        d4[t]       = s4[t];
        d4[256 + t] = s4[256 + t];
    }

    // ---- A fragments (1 limb). A[m=lane&15][k=q*8+j]; rows blk0+tl*16+n ----
    half8 ah[2][2];
#pragma unroll
    for (int tl = 0; tl < 2; ++tl)
#pragma unroll
        for (int ks = 0; ks < 2; ++ks) {
            const float* pp = x + (size_t)(blk0 + tl * 16 + n) * DIM + ks * 32 + q * 8;
            float4 v0 = *(const float4*)pp, v1 = *(const float4*)(pp + 4);
            ah[tl][ks][0] = (_Float16)v0.x; ah[tl][ks][1] = (_Float16)v0.y;
            ah[tl][ks][2] = (_Float16)v0.z; ah[tl][ks][3] = (_Float16)v0.w;
            ah[tl][ks][4] = (_Float16)v1.x; ah[tl][ks][5] = (_Float16)v1.y;
            ah[tl][ks][6] = (_Float16)v1.z; ah[tl][ks][7] = (_Float16)v1.w;
        }

    unsigned best[8], sec[8];
#pragma unroll
    for (int r = 0; r < 8; ++r) { best[r] = 0u; sec[r] = 0u; }

    // quarter h: tiles of 16 cols, 2 KB each; per-lane frag at lane*16
    const char*  ebase = ehb + (size_t)h * 65536 + (size_t)lane * 16;
    const float* enq   = eng + h * 512 + n;

#pragma unroll 2
    for (int tile = 0; tile < 32; ++tile) {
        half8 b0 = *(const half8*)(ebase + tile * 2048);
        half8 b1 = *(const half8*)(ebase + tile * 2048 + 1024);
        const float en = enq[tile * 16];

        floatx4 A0 = {en, en, en, en};   // rows 0-15
        floatx4 A1 = {en, en, en, en};   // rows 16-31
        A0 = __builtin_amdgcn_mfma_f32_16x16x32_f16(ah[0][0], b0, A0, 0, 0, 0);
        A1 = __builtin_amdgcn_mfma_f32_16x16x32_f16(ah[1][0], b0, A1, 0, 0, 0);
        A0 = __builtin_amdgcn_mfma_f32_16x16x32_f16(ah[0][1], b1, A0, 0, 0, 0);
        A1 = __builtin_amdgcn_mfma_f32_16x16x32_f16(ah[1][1], b1, A1, 0, 0, 0);

        const unsigned Lp = (unsigned)(63 - tile);
#pragma unroll
        for (int r = 0; r < 8; ++r) {
            float v = (r < 4) ? A0[r] : A1[r - 4];
            unsigned key = (__float_as_uint(v) & 0xFFFFFFC0u) | Lp;  // v_and_or_b32
            unsigned lo  = umin2(best[r], key);
            best[r] = umax2(best[r], key);
            sec[r]  = umax2(sec[r], lo);
        }
    }

    // ---- decode per-lane top-2 to (bucketed bits, full col) ----
    unsigned bval[8], bcol[8], sval[8], scol[8];
#pragma unroll
    for (int r = 0; r < 8; ++r) {
        bval[r] = best[r] & 0xFFFFFFC0u;
        bcol[r] = (unsigned)(h * 512 + (63 - (int)(best[r] & 63u)) * 16 + n);
        sval[r] = sec[r] & 0xFFFFFFC0u;
        scol[r] = (unsigned)(h * 512 + (63 - (int)(sec[r] & 63u)) * 16 + n);
    }
    // ---- butterfly top-2 merge across the 16 n-lanes of each q-group ----
#pragma unroll
    for (int m = 1; m < 16; m <<= 1) {
#pragma unroll
        for (int r = 0; r < 8; ++r) {
            unsigned ov  = (unsigned)__shfl_xor((int)bval[r], m, 64);
            unsigned oc  = (unsigned)__shfl_xor((int)bcol[r], m, 64);
            unsigned ov2 = (unsigned)__shfl_xor((int)sval[r], m, 64);
            unsigned oc2 = (unsigned)__shfl_xor((int)scol[r], m, 64);
            bool ow = (ov > bval[r]) || (ov == bval[r] && oc < bcol[r]);
            unsigned nbv = ow ? ov : bval[r], nbc = ow ? oc : bcol[r];
            unsigned lv  = ow ? bval[r] : ov, lc  = ow ? bcol[r] : oc;
            bool sv2 = (ov2 > sval[r]) || (ov2 == sval[r] && oc2 < scol[r]);
            unsigned bsv = sv2 ? ov2 : sval[r], bsc = sv2 ? oc2 : scol[r];
            bool s3 = (lv > bsv) || (lv == bsv && lc < bsc);
            sval[r] = s3 ? lv : bsv; scol[r] = s3 ? lc : bsc;
            bval[r] = nbv; bcol[r] = nbc;
        }
    }
    // ---- publish per-quarter candidates (local row = (r>>2)*16 + q*4 + r&3) ----
    if (n == 0) {
#pragma unroll
        for (int r = 0; r < 8; ++r) {
            const int lr = (r >> 2) * 16 + q * 4 + (r & 3);
            Mrg[h][lr] = make_uint4(bval[r], bcol[r], sval[r], scol[r]);
        }
    }
    __syncthreads();

    // ---- exact fp32 rescore of 8 candidates; wave h: rows [h*8, h*8+8) ----
#pragma unroll
    for (int rr = 0; rr < 2; ++rr) {
        const int lr   = h * 8 + q * 2 + rr;
        const int grow = blk0 + lr;
        int cand[8];
#pragma unroll
        for (int g = 0; g < 4; ++g) {
            uint4 cv = Mrg[g][lr];
            cand[g * 2 + 0] = (int)cv.y;
            cand[g * 2 + 1] = (int)cv.w;
        }
        float4 xv = *(const float4*)(x + (size_t)grow * DIM + n * 4);
        float pbest = -FLT_MAX; int cbest = 0;
        float4 ebest = {0.f, 0.f, 0.f, 0.f};
#pragma unroll
        for (int c = 0; c < 8; ++c) {
            float4 e = *(const float4*)(emb + (size_t)cand[c] * DIM + n * 4);
            float pp = (xv.x - 0.5f * e.x) * e.x + (xv.y - 0.5f * e.y) * e.y
                     + (xv.z - 0.5f * e.z) * e.z + (xv.w - 0.5f * e.w) * e.w;
#pragma unroll
            for (int m2 = 1; m2 < 16; m2 <<= 1) pp += __shfl_xor(pp, m2, 64);
            bool take = (pp > pbest) || (pp == pbest && cand[c] < cbest);
            pbest = take ? pp : pbest;
            cbest = take ? cand[c] : cbest;
            ebest.x = take ? e.x : ebest.x; ebest.y = take ? e.y : ebest.y;
            ebest.z = take ? e.z : ebest.z; ebest.w = take ? e.w : ebest.w;
        }
        *(float4*)(quant + (size_t)grow * DIM + n * 4) = ebest;
        if (n == 0) idxf[grow] = (float)cbest;
    }
}

extern "C" void kernel_launch(void* const* d_in, const int* in_sizes, int n_in,
                              void* d_out, int out_size, void* d_ws, size_t ws_size,
                              hipStream_t stream) {
    const float* x   = (const float*)d_in[0];   // [65536, 64]
    const float* emb = (const float*)d_in[1];   // [2048, 64]
    float* out   = (float*)d_out;
    float* quant = out;                               // 4194304 floats
    float* idxf  = out + (size_t)N_TOTAL * DIM;       // 65536 floats
    float* flat  = idxf + N_TOTAL;                    // 4194304 floats

    half8* ehp = (half8*)d_ws;                        // 2048*64 f16 frag-major (256 KB)
    float* en  = (float*)((char*)d_ws + (size_t)NEMB * DIM * 2);  // 2048 f32 (folded)

    prep_kernel<<<64, 256, 0, stream>>>(emb, ehp, en);
    vq_mfma_kernel<<<N_TOTAL / 32, 256, 0, stream>>>(x, emb, (const char*)ehp, en,
                                                     quant, idxf, flat);
}